// Round 1
// baseline (754.410 us; speedup 1.0000x reference)
//
#include <hip/hip_runtime.h>
#include <cstdio>

typedef unsigned short u16;
typedef unsigned int u32;
typedef __attribute__((ext_vector_type(8))) short bf16x8;
typedef __attribute__((ext_vector_type(4))) float f32x4;

static constexpr int T = 8192;   // tokens = B*S
static constexpr int D = 1024;
static constexpr int F = 4096;
static constexpr int E = 8;

__device__ __forceinline__ u16 f2b(float f) {
  u32 u = __float_as_uint(f);
  u32 r = (u + 0x7fffu + ((u >> 16) & 1u)) >> 16;  // RNE
  return (u16)r;
}
__device__ __forceinline__ float b2f(u16 u) {
  return __uint_as_float(((u32)u) << 16);
}

// ---------------- x -> bf16 (vectorized) ----------------
__global__ void convert_x_kernel(const float* __restrict__ x, u16* __restrict__ xb) {
  int idx = blockIdx.x * 256 + threadIdx.x;       // T*D/8 threads exactly
  const float4* p = (const float4*)(x + (size_t)idx * 8);
  float4 a = p[0], b = p[1];
  union { u16 s[8]; uint4 v; } pk;
  pk.s[0] = f2b(a.x); pk.s[1] = f2b(a.y); pk.s[2] = f2b(a.z); pk.s[3] = f2b(a.w);
  pk.s[4] = f2b(b.x); pk.s[5] = f2b(b.y); pk.s[6] = f2b(b.z); pk.s[7] = f2b(b.w);
  *(uint4*)(xb + (size_t)idx * 8) = pk.v;
}

// ---------------- weight transpose + bf16 convert: [E][R][C] -> [E][C][R] ----------------
template<int R, int C>
__global__ void transpose_cvt_kernel(const float* __restrict__ in, u16* __restrict__ outp) {
  __shared__ float tile[64][65];
  const size_t base = (size_t)blockIdx.z * R * C;
  const int r0 = blockIdx.y * 64, c0 = blockIdx.x * 64;
  const int tx = threadIdx.x & 63, tg = threadIdx.x >> 6;
#pragma unroll
  for (int i = 0; i < 16; ++i) {
    int r = i * 4 + tg;
    tile[r][tx] = in[base + (size_t)(r0 + r) * C + (c0 + tx)];
  }
  __syncthreads();
#pragma unroll
  for (int i = 0; i < 16; ++i) {
    int r = i * 4 + tg;
    outp[base + (size_t)(c0 + r) * R + (r0 + tx)] = f2b(tile[tx][r]);
  }
}

// ---------------- gate: logits (fp64), top-2, softmax, counts ----------------
__global__ void gate_kernel(const float* __restrict__ x, const float* __restrict__ gw,
                            int* __restrict__ tki, float* __restrict__ tkw,
                            int* __restrict__ counts) {
  const int lane = threadIdx.x & 63;
  const int t = blockIdx.x * 4 + (threadIdx.x >> 6);
  const float* xr = x + (size_t)t * D;
  double acc[8] = {0, 0, 0, 0, 0, 0, 0, 0};
  for (int i = 0; i < D / 64; ++i) {
    int d = i * 64 + lane;
    double xv = (double)xr[d];
    const float4* g = (const float4*)(gw + (size_t)d * 8);
    float4 g0 = g[0], g1 = g[1];
    acc[0] += xv * (double)g0.x; acc[1] += xv * (double)g0.y;
    acc[2] += xv * (double)g0.z; acc[3] += xv * (double)g0.w;
    acc[4] += xv * (double)g1.x; acc[5] += xv * (double)g1.y;
    acc[6] += xv * (double)g1.z; acc[7] += xv * (double)g1.w;
  }
#pragma unroll
  for (int s = 1; s < 64; s <<= 1) {
#pragma unroll
    for (int e = 0; e < 8; ++e) acc[e] += __shfl_xor(acc[e], s, 64);
  }
  if (lane == 0) {
    int i0 = 0; double l0 = acc[0];
#pragma unroll
    for (int e = 1; e < 8; ++e) if (acc[e] > l0) { l0 = acc[e]; i0 = e; }
    int i1 = -1; double l1 = -1e300;
#pragma unroll
    for (int e = 0; e < 8; ++e) if (e != i0 && acc[e] > l1) { l1 = acc[e]; i1 = e; }
    float w0 = (float)(1.0 / (1.0 + exp(l1 - l0)));  // softmax over {l0,l1}
    float w1f = 1.0f - w0;
    tki[t * 2] = i0; tki[t * 2 + 1] = i1;
    tkw[t * 2] = w0; tkw[t * 2 + 1] = w1f;
    atomicAdd(&counts[i0], 1);
    atomicAdd(&counts[i1], 1);
  }
}

// ---------------- offsets (exclusive prefix) ----------------
__global__ void offsets_kernel(const int* __restrict__ counts, int* __restrict__ offs,
                               int* __restrict__ cursors) {
  if (threadIdx.x == 0) {
    int s = 0;
    for (int e = 0; e < E; ++e) { offs[e] = s; cursors[e] = s; s += counts[e]; }
    offs[E] = s;
  }
}

// ---------------- build compact per-expert token lists ----------------
__global__ void build_lists_kernel(const int* __restrict__ tki, const float* __restrict__ tkw,
                                   int* __restrict__ cursors, int* __restrict__ lst,
                                   float* __restrict__ lsw, int* __restrict__ pos_of) {
  int t = blockIdx.x * 256 + threadIdx.x;
#pragma unroll
  for (int j = 0; j < 2; ++j) {
    int e = tki[t * 2 + j];
    int p = atomicAdd(&cursors[e], 1);
    lst[p] = t;
    lsw[p] = tkw[t * 2 + j];
    pos_of[t * 2 + j] = p;
  }
}

// ---------------- grouped GEMM: [cnt, KD] x [KD, ND] per expert ----------------
// A rows gathered (G1: via token list from xb) or compact (G2: h rows).
// B is pre-transposed bf16: Bt[e][n][k]. LDS tiles XOR-swizzled (G4 recipe).
template<int KD, int ND, bool G1>
__global__ __launch_bounds__(256, 2) void moe_gemm(
    const u16* __restrict__ Abase, const u16* __restrict__ Bt, u16* __restrict__ Out,
    const int* __restrict__ offs, const int* __restrict__ lst,
    const float* __restrict__ lsw) {
  __shared__ u16 As[128 * 64];
  __shared__ u16 Bs[128 * 64];
  const int e = blockIdx.z;
  const int off = offs[e];
  const int cnt = offs[e + 1] - off;
  const int m0 = blockIdx.y * 128;
  if (m0 >= cnt) return;
  const int n0 = blockIdx.x * 128;
  const int tid = threadIdx.x;
  const int lane = tid & 63;
  const int wm = tid >> 7;          // wave row (0..1), 64 rows each
  const int wn = (tid >> 6) & 1;    // wave col (0..1), 64 cols each

  f32x4 zero4 = {0.f, 0.f, 0.f, 0.f};
  f32x4 acc[4][4];
#pragma unroll
  for (int i = 0; i < 4; ++i)
#pragma unroll
    for (int j = 0; j < 4; ++j) acc[i][j] = zero4;

  // Precompute per-thread staging addresses (row/col fixed across K-tiles).
  const size_t bbase = (size_t)e * ND * (size_t)KD;
  size_t abyte[4], bbyte[4];
  int swb[4];
#pragma unroll
  for (int i = 0; i < 4; ++i) {
    int linear = i * 256 + tid;
    int row = linear >> 3;          // 0..127
    int cb = (linear & 7) * 16;     // byte offset within 128B row
    int rr = m0 + row; if (rr >= cnt) rr = cnt - 1;   // clamp; epilogue guards writes
    size_t arow = G1 ? (size_t)lst[off + rr] * KD : (size_t)(off + rr) * KD;
    abyte[i] = arow * 2 + (size_t)cb;
    bbyte[i] = (bbase + (size_t)(n0 + row) * KD) * 2 + (size_t)cb;
    swb[i] = row * 128 + (cb ^ ((row & 7) << 4));
  }

  for (int kt = 0; kt < KD / 64; ++kt) {
    const size_t kb = (size_t)kt * 128;   // 64 bf16 = 128 bytes
    __syncthreads();
#pragma unroll
    for (int i = 0; i < 4; ++i) {
      uint4 av = *(const uint4*)((const char*)Abase + abyte[i] + kb);
      uint4 bv = *(const uint4*)((const char*)Bt + bbyte[i] + kb);
      *(uint4*)((char*)As + swb[i]) = av;
      *(uint4*)((char*)Bs + swb[i]) = bv;
    }
    __syncthreads();
#pragma unroll
    for (int ks = 0; ks < 2; ++ks) {
      const int kbyte = ks * 64 + (lane >> 4) * 16;
      bf16x8 af[4], bfv[4];
#pragma unroll
      for (int mf = 0; mf < 4; ++mf) {
        int row = wm * 64 + mf * 16 + (lane & 15);
        af[mf] = *(const bf16x8*)((const char*)As + row * 128 + (kbyte ^ ((row & 7) << 4)));
      }
#pragma unroll
      for (int nf = 0; nf < 4; ++nf) {
        int row = wn * 64 + nf * 16 + (lane & 15);
        bfv[nf] = *(const bf16x8*)((const char*)Bs + row * 128 + (kbyte ^ ((row & 7) << 4)));
      }
#pragma unroll
      for (int mf = 0; mf < 4; ++mf)
#pragma unroll
        for (int nf = 0; nf < 4; ++nf)
          acc[mf][nf] = __builtin_amdgcn_mfma_f32_16x16x32_bf16(af[mf], bfv[nf], acc[mf][nf], 0, 0, 0);
    }
  }

  // Epilogue: C/D map col=lane&15, row=(lane>>4)*4+reg
#pragma unroll
  for (int mf = 0; mf < 4; ++mf) {
#pragma unroll
    for (int r = 0; r < 4; ++r) {
      int row = wm * 64 + mf * 16 + (lane >> 4) * 4 + r;
      int grow = m0 + row;
      if (grow >= cnt) continue;
      float wgt = G1 ? 1.f : lsw[off + grow];
      size_t obase = (size_t)(off + grow) * ND;
#pragma unroll
      for (int nf = 0; nf < 4; ++nf) {
        float v = acc[mf][nf][r];
        if (G1) v = v / (1.f + __expf(-v));   // silu
        else v *= wgt;
        Out[obase + n0 + wn * 64 + nf * 16 + (lane & 15)] = f2b(v);
      }
    }
  }
}

// ---------------- final combine: out[t] = y[pos0[t]] + y[pos1[t]] ----------------
__global__ void combine_kernel(const u16* __restrict__ y, const int* __restrict__ pos_of,
                               float* __restrict__ outp) {
  int idx = blockIdx.x * 256 + threadIdx.x;   // T*D/8 threads
  int t = idx >> 7;                           // D/8 = 128 chunks per token
  int c = (idx & 127) * 8;
  int p0 = pos_of[t * 2], p1 = pos_of[t * 2 + 1];
  union { uint4 v; u16 s[8]; } a, b;
  a.v = *(const uint4*)(y + (size_t)p0 * D + c);
  b.v = *(const uint4*)(y + (size_t)p1 * D + c);
  float4 r0, r1;
  r0.x = b2f(a.s[0]) + b2f(b.s[0]); r0.y = b2f(a.s[1]) + b2f(b.s[1]);
  r0.z = b2f(a.s[2]) + b2f(b.s[2]); r0.w = b2f(a.s[3]) + b2f(b.s[3]);
  r1.x = b2f(a.s[4]) + b2f(b.s[4]); r1.y = b2f(a.s[5]) + b2f(b.s[5]);
  r1.z = b2f(a.s[6]) + b2f(b.s[6]); r1.w = b2f(a.s[7]) + b2f(b.s[7]);
  *(float4*)(outp + (size_t)t * D + c) = r0;
  *(float4*)(outp + (size_t)t * D + c + 4) = r1;
}

extern "C" void kernel_launch(void* const* d_in, const int* in_sizes, int n_in,
                              void* d_out, int out_size, void* d_ws, size_t ws_size,
                              hipStream_t stream) {
  const float* x  = (const float*)d_in[0];
  const float* gw = (const float*)d_in[1];
  const float* w1 = (const float*)d_in[2];
  const float* w2 = (const float*)d_in[3];
  float* outp = (float*)d_out;

  char* ws = (char*)d_ws;
  size_t o = 0;
  auto alloc = [&](size_t b) { size_t r = o; o += (b + 255) & ~(size_t)255; return r; };
  size_t counts_o = alloc(E * 4);
  size_t offs_o   = alloc((E + 1) * 4);
  size_t curs_o   = alloc(E * 4);
  size_t tki_o    = alloc((size_t)T * 2 * 4);
  size_t tkw_o    = alloc((size_t)T * 2 * 4);
  size_t lst_o    = alloc((size_t)T * 2 * 4);
  size_t lsw_o    = alloc((size_t)T * 2 * 4);
  size_t pos_o    = alloc((size_t)T * 2 * 4);
  size_t xb_o     = alloc((size_t)T * D * 2);
  size_t w1t_o    = alloc((size_t)E * D * F * 2);
  size_t w2t_o    = alloc((size_t)E * D * F * 2);
  size_t h_o      = alloc((size_t)T * 2 * F * 2);
  size_t y_o      = alloc((size_t)T * 2 * D * 2);
  if (o > ws_size) {
    fprintf(stderr, "kernel_launch: ws too small (need %zu, have %zu)\n", o, ws_size);
    return;  // leaves d_out zero -> absmax ~1.8 signature
  }

  int*   counts  = (int*)(ws + counts_o);
  int*   offs    = (int*)(ws + offs_o);
  int*   cursors = (int*)(ws + curs_o);
  int*   tki     = (int*)(ws + tki_o);
  float* tkw     = (float*)(ws + tkw_o);
  int*   lst     = (int*)(ws + lst_o);
  float* lsw     = (float*)(ws + lsw_o);
  int*   pos_of  = (int*)(ws + pos_o);
  u16*   xb      = (u16*)(ws + xb_o);
  u16*   w1t     = (u16*)(ws + w1t_o);
  u16*   w2t     = (u16*)(ws + w2t_o);
  u16*   h       = (u16*)(ws + h_o);
  u16*   y       = (u16*)(ws + y_o);

  hipMemsetAsync(counts, 0, E * 4, stream);
  convert_x_kernel<<<T * D / 8 / 256, 256, 0, stream>>>(x, xb);
  transpose_cvt_kernel<D, F><<<dim3(F / 64, D / 64, E), 256, 0, stream>>>(w1, w1t);
  transpose_cvt_kernel<F, D><<<dim3(D / 64, F / 64, E), 256, 0, stream>>>(w2, w2t);
  gate_kernel<<<T / 4, 256, 0, stream>>>(x, gw, tki, tkw, counts);
  offsets_kernel<<<1, 64, 0, stream>>>(counts, offs, cursors);
  build_lists_kernel<<<T / 256, 256, 0, stream>>>(tki, tkw, cursors, lst, lsw, pos_of);
  moe_gemm<D, F, true><<<dim3(F / 128, T / 128, E), 256, 0, stream>>>(xb, w1t, h, offs, lst, lsw);
  moe_gemm<F, D, false><<<dim3(D / 128, T / 128, E), 256, 0, stream>>>(h, w2t, y, offs, lst, lsw);
  combine_kernel<<<T * D / 8 / 256, 256, 0, stream>>>(y, pos_of, outp);
}

// Round 2
// 725.142 us; speedup vs baseline: 1.0404x; 1.0404x over previous
//
#include <hip/hip_runtime.h>
#include <cstdio>

typedef unsigned short u16;
typedef unsigned int u32;
typedef __attribute__((ext_vector_type(8))) short bf16x8;
typedef __attribute__((ext_vector_type(4))) float f32x4;

static constexpr int T = 8192;   // tokens = B*S
static constexpr int D = 1024;
static constexpr int F = 4096;
static constexpr int E = 8;

__device__ __forceinline__ u16 f2b(float f) {
  u32 u = __float_as_uint(f);
  u32 r = (u + 0x7fffu + ((u >> 16) & 1u)) >> 16;  // RNE
  return (u16)r;
}
__device__ __forceinline__ float b2f(u16 u) {
  return __uint_as_float(((u32)u) << 16);
}

// async global->LDS, 16B per lane; dest = wave-uniform base + lane*16 (m104)
__device__ __forceinline__ void gload16(const void* g, void* l) {
  typedef const __attribute__((address_space(1))) void* gp_t;
  typedef __attribute__((address_space(3))) void* lp_t;
  __builtin_amdgcn_global_load_lds((gp_t)(uintptr_t)g, (lp_t)(uintptr_t)l, 16, 0, 0);
}

// ---------------- weight transpose + bf16 convert: [E][R][C] -> [E][C][R] ----------------
template<int R, int C>
__global__ void transpose_cvt_kernel(const float* __restrict__ in, u16* __restrict__ outp) {
  __shared__ float tile[64][65];
  const size_t base = (size_t)blockIdx.z * R * C;
  const int r0 = blockIdx.y * 64, c0 = blockIdx.x * 64;
  const int tx = threadIdx.x & 63, tg = threadIdx.x >> 6;
#pragma unroll
  for (int i = 0; i < 16; ++i) {
    int r = i * 4 + tg;
    tile[r][tx] = in[base + (size_t)(r0 + r) * C + (c0 + tx)];
  }
  __syncthreads();
#pragma unroll
  for (int i = 0; i < 16; ++i) {
    int r = i * 4 + tg;
    outp[base + (size_t)(c0 + r) * R + (r0 + tx)] = f2b(tile[tx][r]);
  }
}

// ---------------- gate: logits (fp64), top-2, softmax, counts; also emits xb ----------------
__global__ void gate_kernel(const float* __restrict__ x, const float* __restrict__ gw,
                            u16* __restrict__ xb,
                            int* __restrict__ tki, float* __restrict__ tkw,
                            int* __restrict__ counts) {
  const int lane = threadIdx.x & 63;
  const int t = blockIdx.x * 4 + (threadIdx.x >> 6);
  const float* xr = x + (size_t)t * D + lane * 16;

  float xv[16];
#pragma unroll
  for (int i = 0; i < 4; ++i) {
    float4 v = ((const float4*)xr)[i];
    xv[i * 4 + 0] = v.x; xv[i * 4 + 1] = v.y; xv[i * 4 + 2] = v.z; xv[i * 4 + 3] = v.w;
  }
  // emit bf16 copy of x
  union { u16 s[16]; uint4 q[2]; } pk;
#pragma unroll
  for (int j = 0; j < 16; ++j) pk.s[j] = f2b(xv[j]);
  uint4* xbo = (uint4*)(xb + (size_t)t * D + lane * 16);
  xbo[0] = pk.q[0]; xbo[1] = pk.q[1];

  double acc[8] = {0, 0, 0, 0, 0, 0, 0, 0};
  const float4* gwp = (const float4*)(gw + (size_t)(lane * 16) * 8);
#pragma unroll
  for (int j = 0; j < 16; ++j) {
    double xd = (double)xv[j];
    float4 g0 = gwp[j * 2], g1 = gwp[j * 2 + 1];
    acc[0] += xd * (double)g0.x; acc[1] += xd * (double)g0.y;
    acc[2] += xd * (double)g0.z; acc[3] += xd * (double)g0.w;
    acc[4] += xd * (double)g1.x; acc[5] += xd * (double)g1.y;
    acc[6] += xd * (double)g1.z; acc[7] += xd * (double)g1.w;
  }
#pragma unroll
  for (int s = 1; s < 64; s <<= 1) {
#pragma unroll
    for (int e = 0; e < 8; ++e) acc[e] += __shfl_xor(acc[e], s, 64);
  }
  if (lane == 0) {
    int i0 = 0; double l0 = acc[0];
#pragma unroll
    for (int e = 1; e < 8; ++e) if (acc[e] > l0) { l0 = acc[e]; i0 = e; }
    int i1 = -1; double l1 = -1e300;
#pragma unroll
    for (int e = 0; e < 8; ++e) if (e != i0 && acc[e] > l1) { l1 = acc[e]; i1 = e; }
    float w0 = (float)(1.0 / (1.0 + exp(l1 - l0)));  // softmax over {l0,l1}
    float w1f = 1.0f - w0;
    tki[t * 2] = i0; tki[t * 2 + 1] = i1;
    tkw[t * 2] = w0; tkw[t * 2 + 1] = w1f;
    atomicAdd(&counts[i0], 1);
    atomicAdd(&counts[i1], 1);
  }
}

// ---------------- offsets (exclusive prefix) ----------------
__global__ void offsets_kernel(const int* __restrict__ counts, int* __restrict__ offs,
                               int* __restrict__ cursors) {
  if (threadIdx.x == 0) {
    int s = 0;
    for (int e = 0; e < E; ++e) { offs[e] = s; cursors[e] = s; s += counts[e]; }
    offs[E] = s;
  }
}

// ---------------- build compact per-expert token lists ----------------
__global__ void build_lists_kernel(const int* __restrict__ tki, const float* __restrict__ tkw,
                                   int* __restrict__ cursors, int* __restrict__ lst,
                                   float* __restrict__ lsw, int* __restrict__ pos_of) {
  int t = blockIdx.x * 256 + threadIdx.x;
#pragma unroll
  for (int j = 0; j < 2; ++j) {
    int e = tki[t * 2 + j];
    int p = atomicAdd(&cursors[e], 1);
    lst[p] = t;
    lsw[p] = tkw[t * 2 + j];
    pos_of[t * 2 + j] = p;
  }
}

// ---------------- grouped GEMM: [cnt, KD] x [KD, ND] per expert ----------------
// global_load_lds staging: LINEAR LDS dest + pre-swizzled global source (rule 21),
// swizzled ds_read on the consume side. B pre-transposed bf16: Bt[e][n][k].
template<int KD, int ND, bool G1>
__global__ __launch_bounds__(256, 2) void moe_gemm(
    const u16* __restrict__ Abase, const u16* __restrict__ Bt, u16* __restrict__ Out,
    const int* __restrict__ offs, const int* __restrict__ lst,
    const float* __restrict__ lsw) {
  __shared__ u16 As[128 * 64];
  __shared__ u16 Bs[128 * 64];
  const int e = blockIdx.z;
  const int off = offs[e];
  const int cnt = offs[e + 1] - off;
  const int m0 = blockIdx.y * 128;
  if (m0 >= cnt) return;
  const int n0 = blockIdx.x * 128;
  const int tid = threadIdx.x;
  const int lane = tid & 63;
  const int wm = tid >> 7;          // wave row (0..1), 64 rows each
  const int wn = (tid >> 6) & 1;    // wave col (0..1), 64 cols each

  f32x4 zero4 = {0.f, 0.f, 0.f, 0.f};
  f32x4 acc[4][4];
#pragma unroll
  for (int i = 0; i < 4; ++i)
#pragma unroll
    for (int j = 0; j < 4; ++j) acc[i][j] = zero4;

  // Per-thread staging source addresses (pre-swizzled columns), fixed across K-tiles.
  const size_t bbase = (size_t)e * ND * (size_t)KD;
  const char* Ac = (const char*)Abase;
  const char* Bc = (const char*)Bt;
  size_t abyte[4], bbyte[4];
  u32 lbase[4];
#pragma unroll
  for (int i = 0; i < 4; ++i) {
    int linear = i * 256 + tid;
    int row = linear >> 3;          // 0..127
    int cb = (linear & 7) * 16;     // byte offset within 128B chunk
    int scb = cb ^ ((row & 7) << 4);  // pre-swizzled source column
    int rr = m0 + row; if (rr >= cnt) rr = cnt - 1;   // clamp; epilogue guards writes
    size_t arow = G1 ? (size_t)lst[off + rr] * KD : (size_t)(off + rr) * KD;
    abyte[i] = arow * 2 + (size_t)scb;
    bbyte[i] = (bbase + (size_t)(n0 + row) * KD) * 2 + (size_t)scb;
    lbase[i] = (u32)((i * 256 + (tid & ~63)) * 16);  // wave-uniform LDS byte base
  }

  for (int kt = 0; kt < KD / 64; ++kt) {
    const size_t kb = (size_t)kt * 128;   // 64 bf16 = 128 bytes
    __syncthreads();
#pragma unroll
    for (int i = 0; i < 4; ++i) {
      gload16(Ac + abyte[i] + kb, (char*)As + lbase[i]);
      gload16(Bc + bbyte[i] + kb, (char*)Bs + lbase[i]);
    }
    __syncthreads();
#pragma unroll
    for (int ks = 0; ks < 2; ++ks) {
      const int kbyte = ks * 64 + (lane >> 4) * 16;
      bf16x8 af[4], bfv[4];
#pragma unroll
      for (int mf = 0; mf < 4; ++mf) {
        int row = wm * 64 + mf * 16 + (lane & 15);
        af[mf] = *(const bf16x8*)((const char*)As + row * 128 + (kbyte ^ ((row & 7) << 4)));
      }
#pragma unroll
      for (int nf = 0; nf < 4; ++nf) {
        int row = wn * 64 + nf * 16 + (lane & 15);
        bfv[nf] = *(const bf16x8*)((const char*)Bs + row * 128 + (kbyte ^ ((row & 7) << 4)));
      }
#pragma unroll
      for (int mf = 0; mf < 4; ++mf)
#pragma unroll
        for (int nf = 0; nf < 4; ++nf)
          acc[mf][nf] = __builtin_amdgcn_mfma_f32_16x16x32_bf16(af[mf], bfv[nf], acc[mf][nf], 0, 0, 0);
    }
  }

  // Epilogue: C/D map col=lane&15, row=(lane>>4)*4+reg
#pragma unroll
  for (int mf = 0; mf < 4; ++mf) {
#pragma unroll
    for (int r = 0; r < 4; ++r) {
      int row = wm * 64 + mf * 16 + (lane >> 4) * 4 + r;
      int grow = m0 + row;
      if (grow >= cnt) continue;
      float wgt = G1 ? 1.f : lsw[off + grow];
      size_t obase = (size_t)(off + grow) * ND;
#pragma unroll
      for (int nf = 0; nf < 4; ++nf) {
        float v = acc[mf][nf][r];
        if (G1) v = v / (1.f + __expf(-v));   // silu
        else v *= wgt;
        Out[obase + n0 + wn * 64 + nf * 16 + (lane & 15)] = f2b(v);
      }
    }
  }
}

// ---------------- final combine: out[t] = y[pos0[t]] + y[pos1[t]] ----------------
__global__ void combine_kernel(const u16* __restrict__ y, const int* __restrict__ pos_of,
                               float* __restrict__ outp) {
  int idx = blockIdx.x * 256 + threadIdx.x;   // T*D/8 threads
  int t = idx >> 7;                           // D/8 = 128 chunks per token
  int c = (idx & 127) * 8;
  int p0 = pos_of[t * 2], p1 = pos_of[t * 2 + 1];
  union { uint4 v; u16 s[8]; } a, b;
  a.v = *(const uint4*)(y + (size_t)p0 * D + c);
  b.v = *(const uint4*)(y + (size_t)p1 * D + c);
  float4 r0, r1;
  r0.x = b2f(a.s[0]) + b2f(b.s[0]); r0.y = b2f(a.s[1]) + b2f(b.s[1]);
  r0.z = b2f(a.s[2]) + b2f(b.s[2]); r0.w = b2f(a.s[3]) + b2f(b.s[3]);
  r1.x = b2f(a.s[4]) + b2f(b.s[4]); r1.y = b2f(a.s[5]) + b2f(b.s[5]);
  r1.z = b2f(a.s[6]) + b2f(b.s[6]); r1.w = b2f(a.s[7]) + b2f(b.s[7]);
  *(float4*)(outp + (size_t)t * D + c) = r0;
  *(float4*)(outp + (size_t)t * D + c + 4) = r1;
}

extern "C" void kernel_launch(void* const* d_in, const int* in_sizes, int n_in,
                              void* d_out, int out_size, void* d_ws, size_t ws_size,
                              hipStream_t stream) {
  const float* x  = (const float*)d_in[0];
  const float* gw = (const float*)d_in[1];
  const float* w1 = (const float*)d_in[2];
  const float* w2 = (const float*)d_in[3];
  float* outp = (float*)d_out;

  char* ws = (char*)d_ws;
  size_t o = 0;
  auto alloc = [&](size_t b) { size_t r = o; o += (b + 255) & ~(size_t)255; return r; };
  size_t counts_o = alloc(E * 4);
  size_t offs_o   = alloc((E + 1) * 4);
  size_t curs_o   = alloc(E * 4);
  size_t tki_o    = alloc((size_t)T * 2 * 4);
  size_t tkw_o    = alloc((size_t)T * 2 * 4);
  size_t lst_o    = alloc((size_t)T * 2 * 4);
  size_t lsw_o    = alloc((size_t)T * 2 * 4);
  size_t pos_o    = alloc((size_t)T * 2 * 4);
  size_t xb_o     = alloc((size_t)T * D * 2);
  size_t w1t_o    = alloc((size_t)E * D * F * 2);
  size_t w2t_o    = alloc((size_t)E * D * F * 2);
  size_t h_o      = alloc((size_t)T * 2 * F * 2);
  size_t y_o      = alloc((size_t)T * 2 * D * 2);
  if (o > ws_size) {
    fprintf(stderr, "kernel_launch: ws too small (need %zu, have %zu)\n", o, ws_size);
    return;
  }

  int*   counts  = (int*)(ws + counts_o);
  int*   offs    = (int*)(ws + offs_o);
  int*   cursors = (int*)(ws + curs_o);
  int*   tki     = (int*)(ws + tki_o);
  float* tkw     = (float*)(ws + tkw_o);
  int*   lst     = (int*)(ws + lst_o);
  float* lsw     = (float*)(ws + lsw_o);
  int*   pos_of  = (int*)(ws + pos_o);
  u16*   xb      = (u16*)(ws + xb_o);
  u16*   w1t     = (u16*)(ws + w1t_o);
  u16*   w2t     = (u16*)(ws + w2t_o);
  u16*   h       = (u16*)(ws + h_o);
  u16*   y       = (u16*)(ws + y_o);

  hipMemsetAsync(counts, 0, E * 4, stream);
  transpose_cvt_kernel<D, F><<<dim3(F / 64, D / 64, E), 256, 0, stream>>>(w1, w1t);
  transpose_cvt_kernel<F, D><<<dim3(D / 64, F / 64, E), 256, 0, stream>>>(w2, w2t);
  gate_kernel<<<T / 4, 256, 0, stream>>>(x, gw, xb, tki, tkw, counts);
  offsets_kernel<<<1, 64, 0, stream>>>(counts, offs, cursors);
  build_lists_kernel<<<T / 256, 256, 0, stream>>>(tki, tkw, cursors, lst, lsw, pos_of);
  moe_gemm<D, F, true><<<dim3(F / 128, T / 128, E), 256, 0, stream>>>(xb, w1t, h, offs, lst, lsw);
  moe_gemm<F, D, false><<<dim3(D / 128, T / 128, E), 256, 0, stream>>>(h, w2t, y, offs, lst, lsw);
  combine_kernel<<<T * D / 8 / 256, 256, 0, stream>>>(y, pos_of, outp);
}